// Round 8
// baseline (270.161 us; speedup 1.0000x reference)
//
#include <hip/hip_runtime.h>
#include <hip/hip_bf16.h>

#define NROWS 8192
#define NDIM  1024
#define ESCALE 8192.0f
#define EINV   (1.0f / 8192.0f)
#define SCALE1 0x7F7F7F7F   // e8m0 = 127 -> 2^0 in every byte

// packed tile constants (16B-inner layout: [kseg16][row(128)][16B])
#define XTILE_B  131072ull   // bytes per packed fp8 x tile: 128 rows * 1024 k
#define PTILE_B  1048576ull  // bytes per packed fp8 E/Vt tile: 128 rows * 8192 k

typedef __attribute__((ext_vector_type(8))) int intx8;
typedef __attribute__((ext_vector_type(4))) int intx4;
typedef __attribute__((ext_vector_type(4))) float floatx4;

// async global->LDS. HW writes to (wave-uniform lds_base) + lane*16.
__device__ __forceinline__ void async16(void* lds, const void* g) {
  __builtin_amdgcn_global_load_lds(
      (const __attribute__((address_space(1))) unsigned int*)g,
      (__attribute__((address_space(3))) unsigned int*)lds, 16, 0, 0);
}

__device__ __forceinline__ unsigned char f2f8(float f) {
  return (unsigned char)(__builtin_amdgcn_cvt_pk_fp8_f32(f, 0.f, 0, false) & 0xff);
}

// counted wait (N loads may stay in flight) + collective barrier + sched pin
#define WAITN_BAR(N)                                          \
  asm volatile("s_waitcnt vmcnt(" #N ")" ::: "memory");       \
  __builtin_amdgcn_s_barrier();                               \
  __builtin_amdgcn_sched_barrier(0)

// read a 32-byte A/B fragment (k = quad*32..+31) from a 16B-inner LDS tile
__device__ __forceinline__ intx8 frag32s(const unsigned char* base, int quad, int row,
                                         int segsz) {
  const intx4 lo = *reinterpret_cast<const intx4*>(base + (2 * quad) * segsz + row * 16);
  const intx4 hi = *reinterpret_cast<const intx4*>(base + (2 * quad + 1) * segsz + row * 16);
  return __builtin_shufflevector(lo, hi, 0, 1, 2, 3, 4, 5, 6, 7);
}

// ------- Kernel 1: row L2-normalize -> fp8(16*x), TILE-PACKED ----------
__global__ __launch_bounds__(256) void k_norm(const float* __restrict__ emb,
                                              unsigned char* __restrict__ xb) {
  __shared__ float red[4];
  __shared__ float s_rinv;
  const int row = blockIdx.x;
  const int t = threadIdx.x;
  const float4 v = reinterpret_cast<const float4*>(emb + (size_t)row * NDIM)[t];
  float ss = v.x * v.x + v.y * v.y + v.z * v.z + v.w * v.w;
#pragma unroll
  for (int off = 32; off > 0; off >>= 1) ss += __shfl_down(ss, off);
  if ((t & 63) == 0) red[t >> 6] = ss;
  __syncthreads();
  if (t == 0) s_rinv = 1.0f / fmaxf(sqrtf(red[0] + red[1] + red[2] + red[3]), 1e-12f);
  __syncthreads();
  const float r16 = 16.0f * s_rinv;
  int pk = __builtin_amdgcn_cvt_pk_fp8_f32(v.x * r16, v.y * r16, 0, false);
  pk = __builtin_amdgcn_cvt_pk_fp8_f32(v.z * r16, v.w * r16, pk, true);
  const int k = t * 4;
  unsigned char* dst = xb + (size_t)(row >> 7) * XTILE_B +
                       (k >> 4) * 2048 + (row & 127) * 16 + (k & 15);
  *reinterpret_cast<int*>(dst) = pk;
}

// ------- Kernel 2: transpose emb -> Vt fp8, TILE-PACKED ----------
__global__ __launch_bounds__(256) void k_tr8(const float* __restrict__ emb,
                                             unsigned char* __restrict__ Vt8) {
  __shared__ float T[64][72];
  const int r0 = blockIdx.x * 64;  // source rows (j of Vt)
  const int c0 = blockIdx.y * 64;  // source cols (d of Vt)
  const int t = threadIdx.x;
#pragma unroll
  for (int p = 0; p < 4; ++p) {
    const int r = (t >> 4) + 16 * p;
    const int c = (t & 15) * 4;
    const float4 v = *reinterpret_cast<const float4*>(emb + (size_t)(r0 + r) * NDIM + c0 + c);
    T[c + 0][r] = v.x; T[c + 1][r] = v.y; T[c + 2][r] = v.z; T[c + 3][r] = v.w;
  }
  __syncthreads();
#pragma unroll
  for (int p = 0; p < 2; ++p) {
    const int d = (t >> 3) + 32 * p;
    const int seg = t & 7;
    const float* src = &T[d][seg * 8];
    int w0 = __builtin_amdgcn_cvt_pk_fp8_f32(src[0], src[1], 0, false);
    w0 = __builtin_amdgcn_cvt_pk_fp8_f32(src[2], src[3], w0, true);
    int w1 = __builtin_amdgcn_cvt_pk_fp8_f32(src[4], src[5], 0, false);
    w1 = __builtin_amdgcn_cvt_pk_fp8_f32(src[6], src[7], w1, true);
    const int dg = c0 + d;          // global d
    const int jg = r0 + seg * 8;    // global j
    unsigned char* dst = Vt8 + (size_t)(dg >> 7) * PTILE_B +
                         (jg >> 4) * 2048 + (dg & 127) * 16 + (jg & 15);
    int2 o; o.x = w0; o.y = w1;
    *reinterpret_cast<int2*>(dst) = o;
  }
}

// ---- Kernel 3a: symmetric S -> E fp8 (packed), triangle grid, MX K=128 ----
// 4-buffer LDS ring, depth-3 prefetch: loads for tile k are issued 3 compute
// phases (~1700-3000 cyc) before use -> covers HBM-class staging latency that
// the 2-buffer depth-1 pipeline exposed every K-step (r7: ~65us stall).
__global__ __launch_bounds__(256) void k_s_sym(const unsigned char* __restrict__ xb,
                                               unsigned char* __restrict__ E,
                                               float* __restrict__ lsum) {
  __shared__ __align__(16) unsigned char smem[131072];  // 4 bufs x (A 16K | B 16K)
  const int tid = threadIdx.x;
  const int lane = tid & 63, w = tid >> 6;
  const int quad = lane >> 4, l15 = lane & 15;
  const int wi = w >> 1, wj = w & 1;

  // XCD-contiguous bijective remap: 2080 blocks = 8 XCD * 260
  const int idx = (blockIdx.x & 7) * 260 + (blockIdx.x >> 3);
  int bj = (int)((sqrtf(8.0f * idx + 1.0f) - 1.0f) * 0.5f);
  while ((bj + 1) * (bj + 2) / 2 <= idx) ++bj;
  while (bj * (bj + 1) / 2 > idx) --bj;
  const int bi = idx - bj * (bj + 1) / 2;
  const int it0 = bi * 128, jt0 = bj * 128;

  floatx4 acc[4][4];
#pragma unroll
  for (int a = 0; a < 4; ++a)
#pragma unroll
    for (int b = 0; b < 4; ++b) acc[a][b] = {0.f, 0.f, 0.f, 0.f};

  const unsigned char* gA = xb + (size_t)bi * XTILE_B + w * 4096 + lane * 16;
  const unsigned char* gB = xb + (size_t)bj * XTILE_B + w * 4096 + lane * 16;

  auto STAGE = [&](int buf) {  // 8 async16 per wave, advances gA/gB one K-tile
    unsigned char* lA = smem + buf * 32768 + w * 4096;
    unsigned char* lB = lA + 16384;
#pragma unroll
    for (int q = 0; q < 4; ++q) {
      async16(lA + q * 1024, gA + q * 1024);
      async16(lB + q * 1024, gB + q * 1024);
    }
    gA += 16384; gB += 16384;
  };
  auto COMPUTE = [&](int buf) {
    const unsigned char* Ab = smem + buf * 32768;
    const unsigned char* Bb = Ab + 16384;
    intx8 bf[4];
#pragma unroll
    for (int fn = 0; fn < 4; ++fn) bf[fn] = frag32s(Bb, quad, wj * 64 + fn * 16 + l15, 2048);
    __builtin_amdgcn_s_setprio(1);
#pragma unroll
    for (int fm = 0; fm < 4; ++fm) {
      const intx8 af = frag32s(Ab, quad, wi * 64 + fm * 16 + l15, 2048);
#pragma unroll
      for (int fn = 0; fn < 4; ++fn)
        acc[fm][fn] = __builtin_amdgcn_mfma_scale_f32_16x16x128_f8f6f4(
            af, bf[fn], acc[fm][fn], 0, 0, 0, SCALE1, 0, SCALE1);
    }
    __builtin_amdgcn_s_setprio(0);
  };

  // 8 K-tiles, ring of 4, depth-3 prefetch. Steady state: 32 loads/wave in
  // flight; vmcnt(24) -> tile k's 8 done, k+1..k+3 stay in flight.
  STAGE(0); STAGE(1); STAGE(2);
#pragma unroll
  for (int k = 0; k < 5; ++k) {
    STAGE((k + 3) & 3);
    WAITN_BAR(24);
    COMPUTE(k & 3);
    __builtin_amdgcn_s_barrier();   // protect ring slot before restage
  }
  WAITN_BAR(16); COMPUTE(1); __builtin_amdgcn_s_barrier();
  WAITN_BAR(8);  COMPUTE(2); __builtin_amdgcn_s_barrier();
  WAITN_BAR(0);  COMPUTE(3);

  // P = exp(10*s - 10); s_raw = 256*s (x scaled by 16 each side)
#pragma unroll
  for (int fm = 0; fm < 4; ++fm)
#pragma unroll
    for (int fn = 0; fn < 4; ++fn)
#pragma unroll
      for (int reg = 0; reg < 4; ++reg) {
        float p = __expf(fmaf(acc[fm][fn][reg], 10.0f / 256.0f, -10.f));
        if (bi == bj &&
            (wi * 64 + fm * 16 + quad * 4 + reg) == (wj * 64 + fn * 16 + l15))
          p = 0.f;
        acc[fm][fn][reg] = p;
      }

  // normal-orientation packed stores + row sums
  unsigned char* Ei = E + (size_t)bi * PTILE_B;
#pragma unroll
  for (int fm = 0; fm < 4; ++fm)
#pragma unroll
    for (int reg = 0; reg < 4; ++reg) {
      const int row = wi * 64 + fm * 16 + quad * 4 + reg;
      float s = 0.f;
#pragma unroll
      for (int fn = 0; fn < 4; ++fn) {
        const float p = acc[fm][fn][reg];
        s += p;
        Ei[((jt0 >> 4) + wj * 4 + fn) * 2048 + row * 16 + l15] = f2f8(p * ESCALE);
      }
#pragma unroll
      for (int m = 1; m < 16; m <<= 1) s += __shfl_xor(s, m);
      if (l15 == 0) unsafeAtomicAdd(&lsum[it0 + row], s);
    }

  if (bi != bj) {  // transposed packed store + col sums
    unsigned char* Ej = E + (size_t)bj * PTILE_B;
#pragma unroll
    for (int fn = 0; fn < 4; ++fn) {
      const int col = wj * 64 + fn * 16 + l15;  // i-local row within tile bj
      float cs = 0.f;
#pragma unroll
      for (int fm = 0; fm < 4; ++fm) {
        int pk = __builtin_amdgcn_cvt_pk_fp8_f32(acc[fm][fn][0] * ESCALE,
                                                 acc[fm][fn][1] * ESCALE, 0, false);
        pk = __builtin_amdgcn_cvt_pk_fp8_f32(acc[fm][fn][2] * ESCALE,
                                             acc[fm][fn][3] * ESCALE, pk, true);
        cs += acc[fm][fn][0] + acc[fm][fn][1] + acc[fm][fn][2] + acc[fm][fn][3];
        *reinterpret_cast<int*>(
            &Ej[((it0 >> 4) + wi * 4 + fm) * 2048 + col * 16 + quad * 4]) = pk;
      }
      cs += __shfl_xor(cs, 16);
      cs += __shfl_xor(cs, 32);
      if (quad == 0) unsafeAtomicAdd(&lsum[jt0 + col], cs);
    }
  }
}

// ---------------- Kernel 3b: full-grid fallback (chunked, packed) ----------
__global__ __launch_bounds__(256) void k_s_full(const unsigned char* __restrict__ xb,
                                                unsigned char* __restrict__ E,
                                                float* __restrict__ lsum, int ch0) {
  __shared__ __align__(16) unsigned char smem[65536];
  const int tid = threadIdx.x;
  const int lane = tid & 63, w = tid >> 6;
  const int quad = lane >> 4, l15 = lane & 15;
  const int wi = w >> 1, wj = w & 1;
  const int bi = blockIdx.x;       // chunk-local i tile
  const int bj = blockIdx.y;       // global j tile
  const int it0 = bi * 128, jt0 = bj * 128;

  floatx4 acc[4][4];
#pragma unroll
  for (int a = 0; a < 4; ++a)
#pragma unroll
    for (int b = 0; b < 4; ++b) acc[a][b] = {0.f, 0.f, 0.f, 0.f};

  const unsigned char* gA =
      xb + (size_t)((ch0 >> 7) + bi) * XTILE_B + w * 4096 + lane * 16;
  const unsigned char* gB = xb + (size_t)bj * XTILE_B + w * 4096 + lane * 16;

  auto STAGE = [&](int buf) {
    unsigned char* lA = smem + buf * 32768 + w * 4096;
    unsigned char* lB = lA + 16384;
#pragma unroll
    for (int q = 0; q < 4; ++q) {
      async16(lA + q * 1024, gA + q * 1024);
      async16(lB + q * 1024, gB + q * 1024);
    }
    gA += 16384; gB += 16384;
  };
  auto COMPUTE = [&](int buf) {
    const unsigned char* Ab = smem + buf * 32768;
    const unsigned char* Bb = Ab + 16384;
    intx8 bf[4];
#pragma unroll
    for (int fn = 0; fn < 4; ++fn)
      bf[fn] = frag32s(Bb, quad, wj * 64 + fn * 16 + l15, 2048);
    __builtin_amdgcn_s_setprio(1);
#pragma unroll
    for (int fm = 0; fm < 4; ++fm) {
      const intx8 af = frag32s(Ab, quad, wi * 64 + fm * 16 + l15, 2048);
#pragma unroll
      for (int fn = 0; fn < 4; ++fn)
        acc[fm][fn] = __builtin_amdgcn_mfma_scale_f32_16x16x128_f8f6f4(
            af, bf[fn], acc[fm][fn], 0, 0, 0, SCALE1, 0, SCALE1);
    }
    __builtin_amdgcn_s_setprio(0);
  };

  STAGE(0);
  __syncthreads();
#pragma unroll
  for (int kk = 0; kk < 6; kk += 2) {
    STAGE(1); COMPUTE(0); __syncthreads();
    STAGE(0); COMPUTE(1); __syncthreads();
  }
  STAGE(1); COMPUTE(0); __syncthreads(); COMPUTE(1);

  unsigned char* Ei = E + (size_t)bi * PTILE_B;
#pragma unroll
  for (int fm = 0; fm < 4; ++fm)
#pragma unroll
    for (int reg = 0; reg < 4; ++reg) {
      const int row = wi * 64 + fm * 16 + quad * 4 + reg;
      float s = 0.f;
#pragma unroll
      for (int fn = 0; fn < 4; ++fn) {
        const int col = jt0 + wj * 64 + fn * 16 + l15;
        float p = __expf(fmaf(acc[fm][fn][reg], 10.0f / 256.0f, -10.f));
        if (ch0 + it0 + row == col) p = 0.f;
        s += p;
        Ei[(col >> 4) * 2048 + row * 16 + (col & 15)] = f2f8(p * ESCALE);
      }
#pragma unroll
      for (int m = 1; m < 16; m <<= 1) s += __shfl_xor(s, m);
      if (l15 == 0) unsafeAtomicAdd(&lsum[ch0 + it0 + row], s);
    }
}

// -------- Kernel 4: out^T = Vt8 @ E^T (MX fp8 K=128, packed operands) ------
// 4-buffer ring, depth-3 prefetch over 64 K-tiles (E is HBM-resident: 64MB).
__global__ __launch_bounds__(256) void k_pv8(const unsigned char* __restrict__ E,
                                             const unsigned char* __restrict__ Vt8,
                                             const float* __restrict__ lsum,
                                             const float* __restrict__ emb,
                                             float* __restrict__ out,
                                             int swz, int ch0) {
  __shared__ __align__(16) unsigned char smem[131072];  // 4 bufs x 32KB
  const int tid = threadIdx.x;
  const int lane = tid & 63, w = tid >> 6;
  const int quad = lane >> 4, l15 = lane & 15;
  const int wi = w >> 1, wj = w & 1;

  int dt, it;
  if (swz) {
    const int n = blockIdx.x;
    const int r = n & 7, q = n >> 3;
    dt = q >> 3; it = (q & 7) * 8 + r;
  } else {
    dt = blockIdx.x; it = blockIdx.y;
  }
  const int dt0 = dt * 128, it0 = it * 128;

  floatx4 acc[4][4];
#pragma unroll
  for (int a = 0; a < 4; ++a)
#pragma unroll
    for (int b = 0; b < 4; ++b) acc[a][b] = {0.f, 0.f, 0.f, 0.f};

  const unsigned char* gA = Vt8 + (size_t)dt * PTILE_B + w * 4096 + lane * 16;
  const unsigned char* gB = E + (size_t)it * PTILE_B + w * 4096 + lane * 16;

  auto STAGE = [&](int buf) {  // 8 async16 per wave, advances one K-tile
    unsigned char* lA = smem + buf * 32768 + w * 4096;
    unsigned char* lB = lA + 16384;
#pragma unroll
    for (int q = 0; q < 4; ++q) {
      async16(lA + q * 1024, gA + q * 1024);
      async16(lB + q * 1024, gB + q * 1024);
    }
    gA += 16384; gB += 16384;
  };
  auto COMPUTE = [&](int buf) {
    const unsigned char* Ab = smem + buf * 32768;
    const unsigned char* Bb = Ab + 16384;
    intx8 bf[4];
#pragma unroll
    for (int fn = 0; fn < 4; ++fn)
      bf[fn] = frag32s(Bb, quad, wj * 64 + fn * 16 + l15, 2048);
    __builtin_amdgcn_s_setprio(1);
#pragma unroll
    for (int fm = 0; fm < 4; ++fm) {
      const intx8 af = frag32s(Ab, quad, wi * 64 + fm * 16 + l15, 2048);
#pragma unroll
      for (int fn = 0; fn < 4; ++fn)
        acc[fm][fn] = __builtin_amdgcn_mfma_scale_f32_16x16x128_f8f6f4(
            af, bf[fn], acc[fm][fn], 0, 0, 0, SCALE1, 0, SCALE1);
    }
    __builtin_amdgcn_s_setprio(0);
  };

  // 64 K-tiles, ring of 4, depth-3 prefetch
  STAGE(0); STAGE(1); STAGE(2);
#pragma unroll 1
  for (int k = 0; k < 61; ++k) {
    STAGE((k + 3) & 3);
    WAITN_BAR(24);
    COMPUTE(k & 3);
    __builtin_amdgcn_s_barrier();   // protect ring slot before restage
  }
  WAITN_BAR(16); COMPUTE(1); __builtin_amdgcn_s_barrier();
  WAITN_BAR(8);  COMPUTE(2); __builtin_amdgcn_s_barrier();
  WAITN_BAR(0);  COMPUTE(3);

#pragma unroll
  for (int fn = 0; fn < 4; ++fn) {
    const int i = it0 + wj * 64 + fn * 16 + l15;
    const float rinv = 1.0f / (1.0f + lsum[ch0 + i]);
#pragma unroll
    for (int fm = 0; fm < 4; ++fm) {
      const int d = dt0 + wi * 64 + fm * 16 + quad * 4;
      const float4 e = *reinterpret_cast<const float4*>(emb + (size_t)(ch0 + i) * NDIM + d);
      float4 o;
      o.x = (e.x + acc[fm][fn][0] * EINV) * rinv;
      o.y = (e.y + acc[fm][fn][1] * EINV) * rinv;
      o.z = (e.z + acc[fm][fn][2] * EINV) * rinv;
      o.w = (e.w + acc[fm][fn][3] * EINV) * rinv;
      *reinterpret_cast<float4*>(out + (size_t)(ch0 + i) * NDIM + d) = o;
    }
  }
}

extern "C" void kernel_launch(void* const* d_in, const int* in_sizes, int n_in,
                              void* d_out, int out_size, void* d_ws, size_t ws_size,
                              hipStream_t stream) {
  const float* emb = (const float*)d_in[0];
  float* out = (float*)d_out;

  unsigned char* xb = (unsigned char*)d_ws;                            // 8 MB packed fp8
  unsigned char* Vt8 = (unsigned char*)((char*)d_ws + (8ull << 20));   // 8 MB packed fp8
  float* lsum = (float*)((char*)d_ws + (16ull << 20));                 // 32 KB
  unsigned char* E = (unsigned char*)((char*)d_ws + (17ull << 20));    // 64 MB packed fp8

  const size_t avail = ws_size > (17ull << 20) ? ws_size - (17ull << 20) : 0;
  int nc = 1;
  while (nc < 64 && ((size_t)(NROWS / nc) * NROWS) > avail) nc <<= 1;
  const int RC = NROWS / nc;

  hipMemsetAsync(lsum, 0, NROWS * sizeof(float), stream);
  k_norm<<<NROWS, 256, 0, stream>>>(emb, xb);
  k_tr8<<<dim3(NROWS / 64, NDIM / 64), 256, 0, stream>>>(emb, Vt8);

  if (nc == 1) {
    const int nt = NROWS / 128;
    k_s_sym<<<nt * (nt + 1) / 2, 256, 0, stream>>>(xb, E, lsum);
    k_pv8<<<512, 256, 0, stream>>>(E, Vt8, lsum, emb, out, 1, 0);
  } else {
    for (int c = 0; c < nc; ++c) {
      const int ch0 = c * RC;
      k_s_full<<<dim3(RC / 128, NROWS / 128), 256, 0, stream>>>(xb, E, lsum, ch0);
      k_pv8<<<dim3(NDIM / 128, RC / 128), 256, 0, stream>>>(E, Vt8, lsum, emb, out, 0, ch0);
    }
  }
}

// Round 9
// 231.511 us; speedup vs baseline: 1.1669x; 1.1669x over previous
//
#include <hip/hip_runtime.h>
#include <hip/hip_bf16.h>

#define NROWS 8192
#define NDIM  1024
#define ESCALE 8192.0f
#define EINV   (1.0f / 8192.0f)
#define SCALE1 0x7F7F7F7F   // e8m0 = 127 -> 2^0 in every byte

// packed tile constants (16B-inner layout: [kseg16][row(128)][16B])
#define XTILE_B  131072ull   // bytes per packed fp8 x tile: 128 rows * 1024 k
#define PTILE_B  1048576ull  // bytes per packed fp8 E/Vt tile: 128 rows * 8192 k

typedef __attribute__((ext_vector_type(8))) int intx8;
typedef __attribute__((ext_vector_type(4))) int intx4;
typedef __attribute__((ext_vector_type(4))) float floatx4;

// async global->LDS. HW writes to (wave-uniform lds_base) + lane*16.
__device__ __forceinline__ void async16(void* lds, const void* g) {
  __builtin_amdgcn_global_load_lds(
      (const __attribute__((address_space(1))) unsigned int*)g,
      (__attribute__((address_space(3))) unsigned int*)lds, 16, 0, 0);
}

__device__ __forceinline__ unsigned char f2f8(float f) {
  return (unsigned char)(__builtin_amdgcn_cvt_pk_fp8_f32(f, 0.f, 0, false) & 0xff);
}

// read a 32-byte A/B fragment (k = quad*32..+31) from a 16B-inner LDS tile
__device__ __forceinline__ intx8 frag32s(const unsigned char* base, int quad, int row,
                                         int segsz) {
  const intx4 lo = *reinterpret_cast<const intx4*>(base + (2 * quad) * segsz + row * 16);
  const intx4 hi = *reinterpret_cast<const intx4*>(base + (2 * quad + 1) * segsz + row * 16);
  return __builtin_shufflevector(lo, hi, 0, 1, 2, 3, 4, 5, 6, 7);
}

// ------- Kernel 1: row L2-normalize -> fp8(16*x), TILE-PACKED ----------
__global__ __launch_bounds__(256) void k_norm(const float* __restrict__ emb,
                                              unsigned char* __restrict__ xb) {
  __shared__ float red[4];
  __shared__ float s_rinv;
  const int row = blockIdx.x;
  const int t = threadIdx.x;
  const float4 v = reinterpret_cast<const float4*>(emb + (size_t)row * NDIM)[t];
  float ss = v.x * v.x + v.y * v.y + v.z * v.z + v.w * v.w;
#pragma unroll
  for (int off = 32; off > 0; off >>= 1) ss += __shfl_down(ss, off);
  if ((t & 63) == 0) red[t >> 6] = ss;
  __syncthreads();
  if (t == 0) s_rinv = 1.0f / fmaxf(sqrtf(red[0] + red[1] + red[2] + red[3]), 1e-12f);
  __syncthreads();
  const float r16 = 16.0f * s_rinv;
  int pk = __builtin_amdgcn_cvt_pk_fp8_f32(v.x * r16, v.y * r16, 0, false);
  pk = __builtin_amdgcn_cvt_pk_fp8_f32(v.z * r16, v.w * r16, pk, true);
  const int k = t * 4;
  unsigned char* dst = xb + (size_t)(row >> 7) * XTILE_B +
                       (k >> 4) * 2048 + (row & 127) * 16 + (k & 15);
  *reinterpret_cast<int*>(dst) = pk;
}

// ------- Kernel 2: transpose emb -> Vt fp8, TILE-PACKED ----------
__global__ __launch_bounds__(256) void k_tr8(const float* __restrict__ emb,
                                             unsigned char* __restrict__ Vt8) {
  __shared__ float T[64][72];
  const int r0 = blockIdx.x * 64;  // source rows (j of Vt)
  const int c0 = blockIdx.y * 64;  // source cols (d of Vt)
  const int t = threadIdx.x;
#pragma unroll
  for (int p = 0; p < 4; ++p) {
    const int r = (t >> 4) + 16 * p;
    const int c = (t & 15) * 4;
    const float4 v = *reinterpret_cast<const float4*>(emb + (size_t)(r0 + r) * NDIM + c0 + c);
    T[c + 0][r] = v.x; T[c + 1][r] = v.y; T[c + 2][r] = v.z; T[c + 3][r] = v.w;
  }
  __syncthreads();
#pragma unroll
  for (int p = 0; p < 2; ++p) {
    const int d = (t >> 3) + 32 * p;
    const int seg = t & 7;
    const float* src = &T[d][seg * 8];
    int w0 = __builtin_amdgcn_cvt_pk_fp8_f32(src[0], src[1], 0, false);
    w0 = __builtin_amdgcn_cvt_pk_fp8_f32(src[2], src[3], w0, true);
    int w1 = __builtin_amdgcn_cvt_pk_fp8_f32(src[4], src[5], 0, false);
    w1 = __builtin_amdgcn_cvt_pk_fp8_f32(src[6], src[7], w1, true);
    const int dg = c0 + d;          // global d
    const int jg = r0 + seg * 8;    // global j
    unsigned char* dst = Vt8 + (size_t)(dg >> 7) * PTILE_B +
                         (jg >> 4) * 2048 + (dg & 127) * 16 + (jg & 15);
    int2 o; o.x = w0; o.y = w1;
    *reinterpret_cast<int2*>(dst) = o;
  }
}

// ---- Kernel 3a: symmetric S -> E fp8 (packed), triangle grid, MX K=128 ----
// LOW-REGISTER VARIANT targeting the 128-reg class -> 2 blocks/CU (8 waves).
// r3-r8 all ran at 1 wave/SIMD (~320 unified regs/wave): zero TLP, 65% stall.
// K-loop working set: acc 64 + bf 16 (fn-halves, B/A re-read per half) + af 8.
// Plain __syncthreads 2-phase: with 2 blocks/CU the other block covers the
// barrier drain (m97/m114 implicit overlap) -- beats manual pipelines (r7/r8).
__global__ __launch_bounds__(256, 2) void k_s_sym(const unsigned char* __restrict__ xb,
                                                  unsigned char* __restrict__ E,
                                                  float* __restrict__ lsum) {
  __shared__ __align__(16) unsigned char smem[65536];  // [buf0: A|B][buf1: A|B]
  const int tid = threadIdx.x;
  const int lane = tid & 63, w = tid >> 6;
  const int quad = lane >> 4, l15 = lane & 15;
  const int wi = w >> 1, wj = w & 1;

  // XCD-contiguous bijective remap: 2080 blocks = 8 XCD * 260
  const int idx = (blockIdx.x & 7) * 260 + (blockIdx.x >> 3);
  int bj = (int)((sqrtf(8.0f * idx + 1.0f) - 1.0f) * 0.5f);
  while ((bj + 1) * (bj + 2) / 2 <= idx) ++bj;
  while (bj * (bj + 1) / 2 > idx) --bj;
  const int bi = idx - bj * (bj + 1) / 2;
  const int it0 = bi * 128, jt0 = bj * 128;

  floatx4 acc[4][4];
#pragma unroll
  for (int a = 0; a < 4; ++a)
#pragma unroll
    for (int b = 0; b < 4; ++b) acc[a][b] = {0.f, 0.f, 0.f, 0.f};

  const unsigned char* gA = xb + (size_t)bi * XTILE_B + w * 4096 + lane * 16;
  const unsigned char* gB = xb + (size_t)bj * XTILE_B + w * 4096 + lane * 16;

  auto STAGE = [&](int buf) {  // 8 async16 per wave
    unsigned char* lA = smem + buf * 32768 + w * 4096;
    unsigned char* lB = lA + 16384;
#pragma unroll
    for (int q = 0; q < 4; ++q) {
      async16(lA + q * 1024, gA + q * 1024);
      async16(lB + q * 1024, gB + q * 1024);
    }
    gA += 16384; gB += 16384;
  };
  auto COMPUTE = [&](int buf) {
    const unsigned char* Ab = smem + buf * 32768;
    const unsigned char* Bb = Ab + 16384;
    __builtin_amdgcn_s_setprio(1);
#pragma unroll
    for (int h = 0; h < 2; ++h) {  // fn-halves: only 2 B-frags live at a time
      const intx8 bf0 = frag32s(Bb, quad, wj * 64 + (2 * h) * 16 + l15, 2048);
      const intx8 bf1 = frag32s(Bb, quad, wj * 64 + (2 * h + 1) * 16 + l15, 2048);
#pragma unroll
      for (int fm = 0; fm < 4; ++fm) {
        const intx8 af = frag32s(Ab, quad, wi * 64 + fm * 16 + l15, 2048);
        acc[fm][2 * h] = __builtin_amdgcn_mfma_scale_f32_16x16x128_f8f6f4(
            af, bf0, acc[fm][2 * h], 0, 0, 0, SCALE1, 0, SCALE1);
        acc[fm][2 * h + 1] = __builtin_amdgcn_mfma_scale_f32_16x16x128_f8f6f4(
            af, bf1, acc[fm][2 * h + 1], 0, 0, 0, SCALE1, 0, SCALE1);
      }
    }
    __builtin_amdgcn_s_setprio(0);
  };

  // 8 K-tiles, 2-phase dbuf (unroll 1 keeps register pressure down)
  STAGE(0);
  __syncthreads();
#pragma unroll 1
  for (int kk = 0; kk < 3; ++kk) {
    STAGE(1); COMPUTE(0); __syncthreads();
    STAGE(0); COMPUTE(1); __syncthreads();
  }
  STAGE(1); COMPUTE(0); __syncthreads(); COMPUTE(1);

  // P = exp(10*s - 10); s_raw = 256*s (x scaled by 16 each side)
#pragma unroll
  for (int fm = 0; fm < 4; ++fm)
#pragma unroll
    for (int fn = 0; fn < 4; ++fn)
#pragma unroll
      for (int reg = 0; reg < 4; ++reg) {
        float p = __expf(fmaf(acc[fm][fn][reg], 10.0f / 256.0f, -10.f));
        if (bi == bj &&
            (wi * 64 + fm * 16 + quad * 4 + reg) == (wj * 64 + fn * 16 + l15))
          p = 0.f;
        acc[fm][fn][reg] = p;
      }

  // normal-orientation packed stores + row sums
  unsigned char* Ei = E + (size_t)bi * PTILE_B;
#pragma unroll
  for (int fm = 0; fm < 4; ++fm)
#pragma unroll
    for (int reg = 0; reg < 4; ++reg) {
      const int row = wi * 64 + fm * 16 + quad * 4 + reg;
      float s = 0.f;
#pragma unroll
      for (int fn = 0; fn < 4; ++fn) {
        const float p = acc[fm][fn][reg];
        s += p;
        Ei[((jt0 >> 4) + wj * 4 + fn) * 2048 + row * 16 + l15] = f2f8(p * ESCALE);
      }
#pragma unroll
      for (int m = 1; m < 16; m <<= 1) s += __shfl_xor(s, m);
      if (l15 == 0) unsafeAtomicAdd(&lsum[it0 + row], s);
    }

  if (bi != bj) {  // transposed packed store + col sums
    unsigned char* Ej = E + (size_t)bj * PTILE_B;
#pragma unroll
    for (int fn = 0; fn < 4; ++fn) {
      const int col = wj * 64 + fn * 16 + l15;  // i-local row within tile bj
      float cs = 0.f;
#pragma unroll
      for (int fm = 0; fm < 4; ++fm) {
        int pk = __builtin_amdgcn_cvt_pk_fp8_f32(acc[fm][fn][0] * ESCALE,
                                                 acc[fm][fn][1] * ESCALE, 0, false);
        pk = __builtin_amdgcn_cvt_pk_fp8_f32(acc[fm][fn][2] * ESCALE,
                                             acc[fm][fn][3] * ESCALE, pk, true);
        cs += acc[fm][fn][0] + acc[fm][fn][1] + acc[fm][fn][2] + acc[fm][fn][3];
        *reinterpret_cast<int*>(
            &Ej[((it0 >> 4) + wi * 4 + fm) * 2048 + col * 16 + quad * 4]) = pk;
      }
      cs += __shfl_xor(cs, 16);
      cs += __shfl_xor(cs, 32);
      if (quad == 0) unsafeAtomicAdd(&lsum[jt0 + col], cs);
    }
  }
}

// ---------------- Kernel 3b: full-grid fallback (chunked, packed) ----------
__global__ __launch_bounds__(256) void k_s_full(const unsigned char* __restrict__ xb,
                                                unsigned char* __restrict__ E,
                                                float* __restrict__ lsum, int ch0) {
  __shared__ __align__(16) unsigned char smem[65536];
  const int tid = threadIdx.x;
  const int lane = tid & 63, w = tid >> 6;
  const int quad = lane >> 4, l15 = lane & 15;
  const int wi = w >> 1, wj = w & 1;
  const int bi = blockIdx.x;       // chunk-local i tile
  const int bj = blockIdx.y;       // global j tile
  const int it0 = bi * 128, jt0 = bj * 128;

  floatx4 acc[4][4];
#pragma unroll
  for (int a = 0; a < 4; ++a)
#pragma unroll
    for (int b = 0; b < 4; ++b) acc[a][b] = {0.f, 0.f, 0.f, 0.f};

  const unsigned char* gA =
      xb + (size_t)((ch0 >> 7) + bi) * XTILE_B + w * 4096 + lane * 16;
  const unsigned char* gB = xb + (size_t)bj * XTILE_B + w * 4096 + lane * 16;

  auto STAGE = [&](int buf) {
    unsigned char* lA = smem + buf * 32768 + w * 4096;
    unsigned char* lB = lA + 16384;
#pragma unroll
    for (int q = 0; q < 4; ++q) {
      async16(lA + q * 1024, gA + q * 1024);
      async16(lB + q * 1024, gB + q * 1024);
    }
    gA += 16384; gB += 16384;
  };
  auto COMPUTE = [&](int buf) {
    const unsigned char* Ab = smem + buf * 32768;
    const unsigned char* Bb = Ab + 16384;
    intx8 bf[4];
#pragma unroll
    for (int fn = 0; fn < 4; ++fn)
      bf[fn] = frag32s(Bb, quad, wj * 64 + fn * 16 + l15, 2048);
    __builtin_amdgcn_s_setprio(1);
#pragma unroll
    for (int fm = 0; fm < 4; ++fm) {
      const intx8 af = frag32s(Ab, quad, wi * 64 + fm * 16 + l15, 2048);
#pragma unroll
      for (int fn = 0; fn < 4; ++fn)
        acc[fm][fn] = __builtin_amdgcn_mfma_scale_f32_16x16x128_f8f6f4(
            af, bf[fn], acc[fm][fn], 0, 0, 0, SCALE1, 0, SCALE1);
    }
    __builtin_amdgcn_s_setprio(0);
  };

  STAGE(0);
  __syncthreads();
#pragma unroll
  for (int kk = 0; kk < 6; kk += 2) {
    STAGE(1); COMPUTE(0); __syncthreads();
    STAGE(0); COMPUTE(1); __syncthreads();
  }
  STAGE(1); COMPUTE(0); __syncthreads(); COMPUTE(1);

  unsigned char* Ei = E + (size_t)bi * PTILE_B;
#pragma unroll
  for (int fm = 0; fm < 4; ++fm)
#pragma unroll
    for (int reg = 0; reg < 4; ++reg) {
      const int row = wi * 64 + fm * 16 + quad * 4 + reg;
      float s = 0.f;
#pragma unroll
      for (int fn = 0; fn < 4; ++fn) {
        const int col = jt0 + wj * 64 + fn * 16 + l15;
        float p = __expf(fmaf(acc[fm][fn][reg], 10.0f / 256.0f, -10.f));
        if (ch0 + it0 + row == col) p = 0.f;
        s += p;
        Ei[(col >> 4) * 2048 + row * 16 + (col & 15)] = f2f8(p * ESCALE);
      }
#pragma unroll
      for (int m = 1; m < 16; m <<= 1) s += __shfl_xor(s, m);
      if (l15 == 0) unsafeAtomicAdd(&lsum[ch0 + it0 + row], s);
    }
}

// -------- Kernel 4: out^T = Vt8 @ E^T (MX fp8 K=128, packed operands) ------
// Same low-register treatment: (256,2), fn-halves, plain 2-phase syncthreads.
__global__ __launch_bounds__(256, 2) void k_pv8(const unsigned char* __restrict__ E,
                                                const unsigned char* __restrict__ Vt8,
                                                const float* __restrict__ lsum,
                                                const float* __restrict__ emb,
                                                float* __restrict__ out,
                                                int swz, int ch0) {
  __shared__ __align__(16) unsigned char smem[65536];
  const int tid = threadIdx.x;
  const int lane = tid & 63, w = tid >> 6;
  const int quad = lane >> 4, l15 = lane & 15;
  const int wi = w >> 1, wj = w & 1;

  int dt, it;
  if (swz) {
    const int n = blockIdx.x;
    const int r = n & 7, q = n >> 3;
    dt = q >> 3; it = (q & 7) * 8 + r;
  } else {
    dt = blockIdx.x; it = blockIdx.y;
  }
  const int dt0 = dt * 128, it0 = it * 128;

  floatx4 acc[4][4];
#pragma unroll
  for (int a = 0; a < 4; ++a)
#pragma unroll
    for (int b = 0; b < 4; ++b) acc[a][b] = {0.f, 0.f, 0.f, 0.f};

  const unsigned char* gA = Vt8 + (size_t)dt * PTILE_B + w * 4096 + lane * 16;
  const unsigned char* gB = E + (size_t)it * PTILE_B + w * 4096 + lane * 16;

  auto STAGE = [&](int buf) {  // 8 async16 per wave
    unsigned char* lA = smem + buf * 32768 + w * 4096;
    unsigned char* lB = lA + 16384;
#pragma unroll
    for (int q = 0; q < 4; ++q) {
      async16(lA + q * 1024, gA + q * 1024);
      async16(lB + q * 1024, gB + q * 1024);
    }
    gA += 16384; gB += 16384;
  };
  auto COMPUTE = [&](int buf) {
    const unsigned char* Ab = smem + buf * 32768;
    const unsigned char* Bb = Ab + 16384;
    __builtin_amdgcn_s_setprio(1);
#pragma unroll
    for (int h = 0; h < 2; ++h) {
      const intx8 bf0 = frag32s(Bb, quad, wj * 64 + (2 * h) * 16 + l15, 2048);
      const intx8 bf1 = frag32s(Bb, quad, wj * 64 + (2 * h + 1) * 16 + l15, 2048);
#pragma unroll
      for (int fm = 0; fm < 4; ++fm) {
        const intx8 af = frag32s(Ab, quad, wi * 64 + fm * 16 + l15, 2048);
        acc[fm][2 * h] = __builtin_amdgcn_mfma_scale_f32_16x16x128_f8f6f4(
            af, bf0, acc[fm][2 * h], 0, 0, 0, SCALE1, 0, SCALE1);
        acc[fm][2 * h + 1] = __builtin_amdgcn_mfma_scale_f32_16x16x128_f8f6f4(
            af, bf1, acc[fm][2 * h + 1], 0, 0, 0, SCALE1, 0, SCALE1);
      }
    }
    __builtin_amdgcn_s_setprio(0);
  };

  // 64 K-tiles, 2-phase dbuf
  STAGE(0);
  __syncthreads();
#pragma unroll 1
  for (int kk = 0; kk < 31; ++kk) {
    STAGE(1); COMPUTE(0); __syncthreads();
    STAGE(0); COMPUTE(1); __syncthreads();
  }
  STAGE(1); COMPUTE(0); __syncthreads(); COMPUTE(1);

#pragma unroll
  for (int fn = 0; fn < 4; ++fn) {
    const int i = it0 + wj * 64 + fn * 16 + l15;
    const float rinv = 1.0f / (1.0f + lsum[ch0 + i]);
#pragma unroll
    for (int fm = 0; fm < 4; ++fm) {
      const int d = dt0 + wi * 64 + fm * 16 + quad * 4;
      const float4 e = *reinterpret_cast<const float4*>(emb + (size_t)(ch0 + i) * NDIM + d);
      float4 o;
      o.x = (e.x + acc[fm][fn][0] * EINV) * rinv;
      o.y = (e.y + acc[fm][fn][1] * EINV) * rinv;
      o.z = (e.z + acc[fm][fn][2] * EINV) * rinv;
      o.w = (e.w + acc[fm][fn][3] * EINV) * rinv;
      *reinterpret_cast<float4*>(out + (size_t)(ch0 + i) * NDIM + d) = o;
    }
  }
}

extern "C" void kernel_launch(void* const* d_in, const int* in_sizes, int n_in,
                              void* d_out, int out_size, void* d_ws, size_t ws_size,
                              hipStream_t stream) {
  const float* emb = (const float*)d_in[0];
  float* out = (float*)d_out;

  unsigned char* xb = (unsigned char*)d_ws;                            // 8 MB packed fp8
  unsigned char* Vt8 = (unsigned char*)((char*)d_ws + (8ull << 20));   // 8 MB packed fp8
  float* lsum = (float*)((char*)d_ws + (16ull << 20));                 // 32 KB
  unsigned char* E = (unsigned char*)((char*)d_ws + (17ull << 20));    // 64 MB packed fp8

  const size_t avail = ws_size > (17ull << 20) ? ws_size - (17ull << 20) : 0;
  int nc = 1;
  while (nc < 64 && ((size_t)(NROWS / nc) * NROWS) > avail) nc <<= 1;
  const int RC = NROWS / nc;

  hipMemsetAsync(lsum, 0, NROWS * sizeof(float), stream);
  k_norm<<<NROWS, 256, 0, stream>>>(emb, xb);
  k_tr8<<<dim3(NROWS / 64, NDIM / 64), 256, 0, stream>>>(emb, Vt8);

  if (nc == 1) {
    const int nt = NROWS / 128;
    k_s_sym<<<nt * (nt + 1) / 2, 256, 0, stream>>>(xb, E, lsum);
    k_pv8<<<512, 256, 0, stream>>>(E, Vt8, lsum, emb, out, 1, 0);
  } else {
    for (int c = 0; c < nc; ++c) {
      const int ch0 = c * RC;
      k_s_full<<<dim3(RC / 128, NROWS / 128), 256, 0, stream>>>(xb, E, lsum, ch0);
      k_pv8<<<dim3(NDIM / 128, RC / 128), 256, 0, stream>>>(E, Vt8, lsum, emb, out, 0, ch0);
    }
  }
}

// Round 10
// 223.309 us; speedup vs baseline: 1.2098x; 1.0367x over previous
//
#include <hip/hip_runtime.h>
#include <hip/hip_bf16.h>

#define NROWS 8192
#define NDIM  1024
#define ESCALE 8192.0f
#define EINV   (1.0f / 8192.0f)
#define SCALE1 0x7F7F7F7F   // e8m0 = 127 -> 2^0 in every byte

// packed tile constants (16B-inner layout: [kseg16][row(128)][16B])
#define XTILE_B  131072ull   // bytes per packed fp8 x tile: 128 rows * 1024 k
#define PTILE_B  1048576ull  // bytes per packed fp8 E/Vt tile: 128 rows * 8192 k

typedef __attribute__((ext_vector_type(8))) int intx8;
typedef __attribute__((ext_vector_type(4))) int intx4;
typedef __attribute__((ext_vector_type(4))) float floatx4;

// async global->LDS. HW writes to (wave-uniform lds_base) + lane*16.
__device__ __forceinline__ void async16(void* lds, const void* g) {
  __builtin_amdgcn_global_load_lds(
      (const __attribute__((address_space(1))) unsigned int*)g,
      (__attribute__((address_space(3))) unsigned int*)lds, 16, 0, 0);
}

__device__ __forceinline__ unsigned char f2f8(float f) {
  return (unsigned char)(__builtin_amdgcn_cvt_pk_fp8_f32(f, 0.f, 0, false) & 0xff);
}

// read a 32-byte A/B fragment (k = quad*32..+31) from a 16B-inner LDS tile
__device__ __forceinline__ intx8 frag32s(const unsigned char* base, int quad, int row,
                                         int segsz) {
  const intx4 lo = *reinterpret_cast<const intx4*>(base + (2 * quad) * segsz + row * 16);
  const intx4 hi = *reinterpret_cast<const intx4*>(base + (2 * quad + 1) * segsz + row * 16);
  return __builtin_shufflevector(lo, hi, 0, 1, 2, 3, 4, 5, 6, 7);
}

// ------- Kernel 1: row L2-normalize -> fp8(16*x), TILE-PACKED ----------
__global__ __launch_bounds__(256) void k_norm(const float* __restrict__ emb,
                                              unsigned char* __restrict__ xb) {
  __shared__ float red[4];
  __shared__ float s_rinv;
  const int row = blockIdx.x;
  const int t = threadIdx.x;
  const float4 v = reinterpret_cast<const float4*>(emb + (size_t)row * NDIM)[t];
  float ss = v.x * v.x + v.y * v.y + v.z * v.z + v.w * v.w;
#pragma unroll
  for (int off = 32; off > 0; off >>= 1) ss += __shfl_down(ss, off);
  if ((t & 63) == 0) red[t >> 6] = ss;
  __syncthreads();
  if (t == 0) s_rinv = 1.0f / fmaxf(sqrtf(red[0] + red[1] + red[2] + red[3]), 1e-12f);
  __syncthreads();
  const float r16 = 16.0f * s_rinv;
  int pk = __builtin_amdgcn_cvt_pk_fp8_f32(v.x * r16, v.y * r16, 0, false);
  pk = __builtin_amdgcn_cvt_pk_fp8_f32(v.z * r16, v.w * r16, pk, true);
  const int k = t * 4;
  unsigned char* dst = xb + (size_t)(row >> 7) * XTILE_B +
                       (k >> 4) * 2048 + (row & 127) * 16 + (k & 15);
  *reinterpret_cast<int*>(dst) = pk;
}

// ------- Kernel 2: transpose emb -> Vt fp8, TILE-PACKED ----------
// Pitch 73 (was 72): 72 gave c*72 === c*8 (mod 32) with c===0 mod 4 -> all 16
// lanes in one bank (16-way conflict) on BOTH phases. 73 -> ~2-way (free).
__global__ __launch_bounds__(256) void k_tr8(const float* __restrict__ emb,
                                             unsigned char* __restrict__ Vt8) {
  __shared__ float T[64][73];
  const int r0 = blockIdx.x * 64;  // source rows (j of Vt)
  const int c0 = blockIdx.y * 64;  // source cols (d of Vt)
  const int t = threadIdx.x;
#pragma unroll
  for (int p = 0; p < 4; ++p) {
    const int r = (t >> 4) + 16 * p;
    const int c = (t & 15) * 4;
    const float4 v = *reinterpret_cast<const float4*>(emb + (size_t)(r0 + r) * NDIM + c0 + c);
    T[c + 0][r] = v.x; T[c + 1][r] = v.y; T[c + 2][r] = v.z; T[c + 3][r] = v.w;
  }
  __syncthreads();
#pragma unroll
  for (int p = 0; p < 2; ++p) {
    const int d = (t >> 3) + 32 * p;
    const int seg = t & 7;
    const float* src = &T[d][seg * 8];
    int w0 = __builtin_amdgcn_cvt_pk_fp8_f32(src[0], src[1], 0, false);
    w0 = __builtin_amdgcn_cvt_pk_fp8_f32(src[2], src[3], w0, true);
    int w1 = __builtin_amdgcn_cvt_pk_fp8_f32(src[4], src[5], 0, false);
    w1 = __builtin_amdgcn_cvt_pk_fp8_f32(src[6], src[7], w1, true);
    const int dg = c0 + d;          // global d
    const int jg = r0 + seg * 8;    // global j
    unsigned char* dst = Vt8 + (size_t)(dg >> 7) * PTILE_B +
                         (jg >> 4) * 2048 + (dg & 127) * 16 + (jg & 15);
    int2 o; o.x = w0; o.y = w1;
    *reinterpret_cast<int2*>(dst) = o;
  }
}

// ---- Kernel 3a: symmetric S -> E fp8 (packed), triangle grid, MX K=128 ----
// (256,2) low-register class (r9: 2 blocks/CU, +40%). This round: af[4]-held
// COMPUTE -> LDS reads/step 24->16 b128 (fn-halves re-read A per half; LDS
// pipe was co-critical with MFMA), each bf feeds 4 MFMAs (better ILP).
__global__ __launch_bounds__(256, 2) void k_s_sym(const unsigned char* __restrict__ xb,
                                                  unsigned char* __restrict__ E,
                                                  float* __restrict__ lsum) {
  __shared__ __align__(16) unsigned char smem[65536];  // [buf0: A|B][buf1: A|B]
  const int tid = threadIdx.x;
  const int lane = tid & 63, w = tid >> 6;
  const int quad = lane >> 4, l15 = lane & 15;
  const int wi = w >> 1, wj = w & 1;

  // XCD-contiguous bijective remap: 2080 blocks = 8 XCD * 260
  const int idx = (blockIdx.x & 7) * 260 + (blockIdx.x >> 3);
  int bj = (int)((sqrtf(8.0f * idx + 1.0f) - 1.0f) * 0.5f);
  while ((bj + 1) * (bj + 2) / 2 <= idx) ++bj;
  while (bj * (bj + 1) / 2 > idx) --bj;
  const int bi = idx - bj * (bj + 1) / 2;
  const int it0 = bi * 128, jt0 = bj * 128;

  floatx4 acc[4][4];
#pragma unroll
  for (int a = 0; a < 4; ++a)
#pragma unroll
    for (int b = 0; b < 4; ++b) acc[a][b] = {0.f, 0.f, 0.f, 0.f};

  const unsigned char* gA = xb + (size_t)bi * XTILE_B + w * 4096 + lane * 16;
  const unsigned char* gB = xb + (size_t)bj * XTILE_B + w * 4096 + lane * 16;

  auto STAGE = [&](int buf) {  // 8 async16 per wave
    unsigned char* lA = smem + buf * 32768 + w * 4096;
    unsigned char* lB = lA + 16384;
#pragma unroll
    for (int q = 0; q < 4; ++q) {
      async16(lA + q * 1024, gA + q * 1024);
      async16(lB + q * 1024, gB + q * 1024);
    }
    gA += 16384; gB += 16384;
  };
  auto COMPUTE = [&](int buf) {
    const unsigned char* Ab = smem + buf * 32768;
    const unsigned char* Bb = Ab + 16384;
    intx8 af[4];
#pragma unroll
    for (int fm = 0; fm < 4; ++fm)
      af[fm] = frag32s(Ab, quad, wi * 64 + fm * 16 + l15, 2048);
    __builtin_amdgcn_s_setprio(1);
#pragma unroll
    for (int fn = 0; fn < 4; ++fn) {
      const intx8 bf = frag32s(Bb, quad, wj * 64 + fn * 16 + l15, 2048);
#pragma unroll
      for (int fm = 0; fm < 4; ++fm)
        acc[fm][fn] = __builtin_amdgcn_mfma_scale_f32_16x16x128_f8f6f4(
            af[fm], bf, acc[fm][fn], 0, 0, 0, SCALE1, 0, SCALE1);
    }
    __builtin_amdgcn_s_setprio(0);
  };

  // 8 K-tiles, 2-phase dbuf (unroll 1 keeps register pressure down)
  STAGE(0);
  __syncthreads();
#pragma unroll 1
  for (int kk = 0; kk < 3; ++kk) {
    STAGE(1); COMPUTE(0); __syncthreads();
    STAGE(0); COMPUTE(1); __syncthreads();
  }
  STAGE(1); COMPUTE(0); __syncthreads(); COMPUTE(1);

  // P = exp(10*s - 10); s_raw = 256*s (x scaled by 16 each side)
#pragma unroll
  for (int fm = 0; fm < 4; ++fm)
#pragma unroll
    for (int fn = 0; fn < 4; ++fn)
#pragma unroll
      for (int reg = 0; reg < 4; ++reg) {
        float p = __expf(fmaf(acc[fm][fn][reg], 10.0f / 256.0f, -10.f));
        if (bi == bj &&
            (wi * 64 + fm * 16 + quad * 4 + reg) == (wj * 64 + fn * 16 + l15))
          p = 0.f;
        acc[fm][fn][reg] = p;
      }

  // normal-orientation packed stores + row sums
  unsigned char* Ei = E + (size_t)bi * PTILE_B;
#pragma unroll
  for (int fm = 0; fm < 4; ++fm)
#pragma unroll
    for (int reg = 0; reg < 4; ++reg) {
      const int row = wi * 64 + fm * 16 + quad * 4 + reg;
      float s = 0.f;
#pragma unroll
      for (int fn = 0; fn < 4; ++fn) {
        const float p = acc[fm][fn][reg];
        s += p;
        Ei[((jt0 >> 4) + wj * 4 + fn) * 2048 + row * 16 + l15] = f2f8(p * ESCALE);
      }
#pragma unroll
      for (int m = 1; m < 16; m <<= 1) s += __shfl_xor(s, m);
      if (l15 == 0) unsafeAtomicAdd(&lsum[it0 + row], s);
    }

  if (bi != bj) {  // transposed packed store + col sums
    unsigned char* Ej = E + (size_t)bj * PTILE_B;
#pragma unroll
    for (int fn = 0; fn < 4; ++fn) {
      const int col = wj * 64 + fn * 16 + l15;  // i-local row within tile bj
      float cs = 0.f;
#pragma unroll
      for (int fm = 0; fm < 4; ++fm) {
        int pk = __builtin_amdgcn_cvt_pk_fp8_f32(acc[fm][fn][0] * ESCALE,
                                                 acc[fm][fn][1] * ESCALE, 0, false);
        pk = __builtin_amdgcn_cvt_pk_fp8_f32(acc[fm][fn][2] * ESCALE,
                                             acc[fm][fn][3] * ESCALE, pk, true);
        cs += acc[fm][fn][0] + acc[fm][fn][1] + acc[fm][fn][2] + acc[fm][fn][3];
        *reinterpret_cast<int*>(
            &Ej[((it0 >> 4) + wi * 4 + fm) * 2048 + col * 16 + quad * 4]) = pk;
      }
      cs += __shfl_xor(cs, 16);
      cs += __shfl_xor(cs, 32);
      if (quad == 0) unsafeAtomicAdd(&lsum[jt0 + col], cs);
    }
  }
}

// ---------------- Kernel 3b: full-grid fallback (chunked, packed) ----------
__global__ __launch_bounds__(256) void k_s_full(const unsigned char* __restrict__ xb,
                                                unsigned char* __restrict__ E,
                                                float* __restrict__ lsum, int ch0) {
  __shared__ __align__(16) unsigned char smem[65536];
  const int tid = threadIdx.x;
  const int lane = tid & 63, w = tid >> 6;
  const int quad = lane >> 4, l15 = lane & 15;
  const int wi = w >> 1, wj = w & 1;
  const int bi = blockIdx.x;       // chunk-local i tile
  const int bj = blockIdx.y;       // global j tile
  const int it0 = bi * 128, jt0 = bj * 128;

  floatx4 acc[4][4];
#pragma unroll
  for (int a = 0; a < 4; ++a)
#pragma unroll
    for (int b = 0; b < 4; ++b) acc[a][b] = {0.f, 0.f, 0.f, 0.f};

  const unsigned char* gA =
      xb + (size_t)((ch0 >> 7) + bi) * XTILE_B + w * 4096 + lane * 16;
  const unsigned char* gB = xb + (size_t)bj * XTILE_B + w * 4096 + lane * 16;

  auto STAGE = [&](int buf) {
    unsigned char* lA = smem + buf * 32768 + w * 4096;
    unsigned char* lB = lA + 16384;
#pragma unroll
    for (int q = 0; q < 4; ++q) {
      async16(lA + q * 1024, gA + q * 1024);
      async16(lB + q * 1024, gB + q * 1024);
    }
    gA += 16384; gB += 16384;
  };
  auto COMPUTE = [&](int buf) {
    const unsigned char* Ab = smem + buf * 32768;
    const unsigned char* Bb = Ab + 16384;
    intx8 bf[4];
#pragma unroll
    for (int fn = 0; fn < 4; ++fn)
      bf[fn] = frag32s(Bb, quad, wj * 64 + fn * 16 + l15, 2048);
    __builtin_amdgcn_s_setprio(1);
#pragma unroll
    for (int fm = 0; fm < 4; ++fm) {
      const intx8 af = frag32s(Ab, quad, wi * 64 + fm * 16 + l15, 2048);
#pragma unroll
      for (int fn = 0; fn < 4; ++fn)
        acc[fm][fn] = __builtin_amdgcn_mfma_scale_f32_16x16x128_f8f6f4(
            af, bf[fn], acc[fm][fn], 0, 0, 0, SCALE1, 0, SCALE1);
    }
    __builtin_amdgcn_s_setprio(0);
  };

  STAGE(0);
  __syncthreads();
#pragma unroll
  for (int kk = 0; kk < 6; kk += 2) {
    STAGE(1); COMPUTE(0); __syncthreads();
    STAGE(0); COMPUTE(1); __syncthreads();
  }
  STAGE(1); COMPUTE(0); __syncthreads(); COMPUTE(1);

  unsigned char* Ei = E + (size_t)bi * PTILE_B;
#pragma unroll
  for (int fm = 0; fm < 4; ++fm)
#pragma unroll
    for (int reg = 0; reg < 4; ++reg) {
      const int row = wi * 64 + fm * 16 + quad * 4 + reg;
      float s = 0.f;
#pragma unroll
      for (int fn = 0; fn < 4; ++fn) {
        const int col = jt0 + wj * 64 + fn * 16 + l15;
        float p = __expf(fmaf(acc[fm][fn][reg], 10.0f / 256.0f, -10.f));
        if (ch0 + it0 + row == col) p = 0.f;
        s += p;
        Ei[(col >> 4) * 2048 + row * 16 + (col & 15)] = f2f8(p * ESCALE);
      }
#pragma unroll
      for (int m = 1; m < 16; m <<= 1) s += __shfl_xor(s, m);
      if (l15 == 0) unsafeAtomicAdd(&lsum[ch0 + it0 + row], s);
    }
}

// -------- Kernel 4: out^T = Vt8 @ E^T (MX fp8 K=128, packed operands) ------
// Unchanged from r9 (control): (256,2), fn-halves, plain 2-phase syncthreads.
__global__ __launch_bounds__(256, 2) void k_pv8(const unsigned char* __restrict__ E,
                                                const unsigned char* __restrict__ Vt8,
                                                const float* __restrict__ lsum,
                                                const float* __restrict__ emb,
                                                float* __restrict__ out,
                                                int swz, int ch0) {
  __shared__ __align__(16) unsigned char smem[65536];
  const int tid = threadIdx.x;
  const int lane = tid & 63, w = tid >> 6;
  const int quad = lane >> 4, l15 = lane & 15;
  const int wi = w >> 1, wj = w & 1;

  int dt, it;
  if (swz) {
    const int n = blockIdx.x;
    const int r = n & 7, q = n >> 3;
    dt = q >> 3; it = (q & 7) * 8 + r;
  } else {
    dt = blockIdx.x; it = blockIdx.y;
  }
  const int dt0 = dt * 128, it0 = it * 128;

  floatx4 acc[4][4];
#pragma unroll
  for (int a = 0; a < 4; ++a)
#pragma unroll
    for (int b = 0; b < 4; ++b) acc[a][b] = {0.f, 0.f, 0.f, 0.f};

  const unsigned char* gA = Vt8 + (size_t)dt * PTILE_B + w * 4096 + lane * 16;
  const unsigned char* gB = E + (size_t)it * PTILE_B + w * 4096 + lane * 16;

  auto STAGE = [&](int buf) {  // 8 async16 per wave
    unsigned char* lA = smem + buf * 32768 + w * 4096;
    unsigned char* lB = lA + 16384;
#pragma unroll
    for (int q = 0; q < 4; ++q) {
      async16(lA + q * 1024, gA + q * 1024);
      async16(lB + q * 1024, gB + q * 1024);
    }
    gA += 16384; gB += 16384;
  };
  auto COMPUTE = [&](int buf) {
    const unsigned char* Ab = smem + buf * 32768;
    const unsigned char* Bb = Ab + 16384;
    __builtin_amdgcn_s_setprio(1);
#pragma unroll
    for (int h = 0; h < 2; ++h) {
      const intx8 bf0 = frag32s(Bb, quad, wj * 64 + (2 * h) * 16 + l15, 2048);
      const intx8 bf1 = frag32s(Bb, quad, wj * 64 + (2 * h + 1) * 16 + l15, 2048);
#pragma unroll
      for (int fm = 0; fm < 4; ++fm) {
        const intx8 af = frag32s(Ab, quad, wi * 64 + fm * 16 + l15, 2048);
        acc[fm][2 * h] = __builtin_amdgcn_mfma_scale_f32_16x16x128_f8f6f4(
            af, bf0, acc[fm][2 * h], 0, 0, 0, SCALE1, 0, SCALE1);
        acc[fm][2 * h + 1] = __builtin_amdgcn_mfma_scale_f32_16x16x128_f8f6f4(
            af, bf1, acc[fm][2 * h + 1], 0, 0, 0, SCALE1, 0, SCALE1);
      }
    }
    __builtin_amdgcn_s_setprio(0);
  };

  // 64 K-tiles, 2-phase dbuf
  STAGE(0);
  __syncthreads();
#pragma unroll 1
  for (int kk = 0; kk < 31; ++kk) {
    STAGE(1); COMPUTE(0); __syncthreads();
    STAGE(0); COMPUTE(1); __syncthreads();
  }
  STAGE(1); COMPUTE(0); __syncthreads(); COMPUTE(1);

#pragma unroll
  for (int fn = 0; fn < 4; ++fn) {
    const int i = it0 + wj * 64 + fn * 16 + l15;
    const float rinv = 1.0f / (1.0f + lsum[ch0 + i]);
#pragma unroll
    for (int fm = 0; fm < 4; ++fm) {
      const int d = dt0 + wi * 64 + fm * 16 + quad * 4;
      const float4 e = *reinterpret_cast<const float4*>(emb + (size_t)(ch0 + i) * NDIM + d);
      float4 o;
      o.x = (e.x + acc[fm][fn][0] * EINV) * rinv;
      o.y = (e.y + acc[fm][fn][1] * EINV) * rinv;
      o.z = (e.z + acc[fm][fn][2] * EINV) * rinv;
      o.w = (e.w + acc[fm][fn][3] * EINV) * rinv;
      *reinterpret_cast<float4*>(out + (size_t)(ch0 + i) * NDIM + d) = o;
    }
  }
}

extern "C" void kernel_launch(void* const* d_in, const int* in_sizes, int n_in,
                              void* d_out, int out_size, void* d_ws, size_t ws_size,
                              hipStream_t stream) {
  const float* emb = (const float*)d_in[0];
  float* out = (float*)d_out;

  unsigned char* xb = (unsigned char*)d_ws;                            // 8 MB packed fp8
  unsigned char* Vt8 = (unsigned char*)((char*)d_ws + (8ull << 20));   // 8 MB packed fp8
  float* lsum = (float*)((char*)d_ws + (16ull << 20));                 // 32 KB
  unsigned char* E = (unsigned char*)((char*)d_ws + (17ull << 20));    // 64 MB packed fp8

  const size_t avail = ws_size > (17ull << 20) ? ws_size - (17ull << 20) : 0;
  int nc = 1;
  while (nc < 64 && ((size_t)(NROWS / nc) * NROWS) > avail) nc <<= 1;
  const int RC = NROWS / nc;

  hipMemsetAsync(lsum, 0, NROWS * sizeof(float), stream);
  k_norm<<<NROWS, 256, 0, stream>>>(emb, xb);
  k_tr8<<<dim3(NROWS / 64, NDIM / 64), 256, 0, stream>>>(emb, Vt8);

  if (nc == 1) {
    const int nt = NROWS / 128;
    k_s_sym<<<nt * (nt + 1) / 2, 256, 0, stream>>>(xb, E, lsum);
    k_pv8<<<512, 256, 0, stream>>>(E, Vt8, lsum, emb, out, 1, 0);
  } else {
    for (int c = 0; c < nc; ++c) {
      const int ch0 = c * RC;
      k_s_full<<<dim3(RC / 128, NROWS / 128), 256, 0, stream>>>(xb, E, lsum, ch0);
      k_pv8<<<dim3(NDIM / 128, RC / 128), 256, 0, stream>>>(E, Vt8, lsum, emb, out, 0, ch0);
    }
  }
}